// Round 1
// baseline (1498.457 us; speedup 1.0000x reference)
//
#include <hip/hip_runtime.h>
#include <hip/hip_bf16.h>
#include <math.h>

#define B_    2
#define T_    2048
#define D_    1024
#define H_    16
#define HD_   64
#define INNER_ 1024
#define SCALE_ 0.125f   // d^-0.5 = 64^-0.5

// ---------------------------------------------------------------------------
// Generic fp32 SGEMM: C(MxN) = A(MxK) @ B(KxN), all row-major.
// 128x128 tile, BK=16, 256 threads, 8x8 micro-tile per thread.
// All problem dims here are multiples of 128/16 -> no bounds checks.
// ---------------------------------------------------------------------------
__global__ __launch_bounds__(256) void sgemm128(
    const float* __restrict__ A, const float* __restrict__ Bm,
    float* __restrict__ C, int M, int N, int K) {
  __shared__ float As[16][128];   // transposed: As[k][m]
  __shared__ float Bs[16][128];   // Bs[k][n]
  const int tid = threadIdx.x;
  const int m0 = blockIdx.y * 128;
  const int n0 = blockIdx.x * 128;
  const int tr = tid >> 4;        // 0..15
  const int tc = tid & 15;        // 0..15
  float acc[8][8];
#pragma unroll
  for (int i = 0; i < 8; ++i)
#pragma unroll
    for (int j = 0; j < 8; ++j) acc[i][j] = 0.f;

  for (int k0 = 0; k0 < K; k0 += 16) {
    // A tile: 128x16 = 2048 elems, 2 float4 per thread
#pragma unroll
    for (int l = 0; l < 2; ++l) {
      int e = tid + l * 256;
      int m = e >> 2;
      int k = (e & 3) << 2;
      float4 av = *reinterpret_cast<const float4*>(A + (size_t)(m0 + m) * K + k0 + k);
      As[k + 0][m] = av.x; As[k + 1][m] = av.y;
      As[k + 2][m] = av.z; As[k + 3][m] = av.w;
    }
    // B tile: 16x128, coalesced float4
#pragma unroll
    for (int l = 0; l < 2; ++l) {
      int k = (tid >> 5) + l * 8;
      int n = (tid & 31) << 2;
      *reinterpret_cast<float4*>(&Bs[k][n]) =
          *reinterpret_cast<const float4*>(Bm + (size_t)(k0 + k) * N + n0 + n);
    }
    __syncthreads();
#pragma unroll
    for (int k = 0; k < 16; ++k) {
      float a[8], b[8];
#pragma unroll
      for (int i = 0; i < 8; ++i) a[i] = As[k][tr * 8 + i];
#pragma unroll
      for (int j = 0; j < 8; ++j) b[j] = Bs[k][tc * 8 + j];
#pragma unroll
      for (int i = 0; i < 8; ++i)
#pragma unroll
        for (int j = 0; j < 8; ++j) acc[i][j] = fmaf(a[i], b[j], acc[i][j]);
    }
    __syncthreads();
  }
#pragma unroll
  for (int i = 0; i < 8; ++i) {
    float* cp = C + (size_t)(m0 + tr * 8 + i) * N + n0 + tc * 8;
#pragma unroll
    for (int j = 0; j < 8; j += 4) {
      *reinterpret_cast<float4*>(cp + j) =
          make_float4(acc[i][j], acc[i][j + 1], acc[i][j + 2], acc[i][j + 3]);
    }
  }
}

// ---------------------------------------------------------------------------
// Pointwise fused kernel, one block per (b,t) row:
//   dt = softplus(x@W_dt + b_dt); gamma_h = exp(-dt)
//   p = sigmoid(praw + b_gsp); gamma_eff = gamma_h*(1-p)+p
//   log_gamma[b,h,t] = log(clip(mean_d(gamma_eff), 1e-6, 1-1e-6))
//   V *= (1-p)   (in-place in qkv buffer)
//   RoPE(Q), RoPE(K) in-place
// ---------------------------------------------------------------------------
__global__ __launch_bounds__(256) void pointwise_kernel(
    const float* __restrict__ x, const float* __restrict__ praw,
    float* __restrict__ qkv, const float* __restrict__ W_dt,
    const float* __restrict__ b_dt, const float* __restrict__ b_gsp,
    const float* __restrict__ inv_freq, float* __restrict__ lg) {
  const int row = blockIdx.x;          // b*T + t
  const int b = row >> 11;             // /T_
  const int t = row & (T_ - 1);
  const int tid = threadIdx.x;
  __shared__ float xs[D_];
  __shared__ float gam[H_];

  *reinterpret_cast<float4*>(&xs[tid * 4]) =
      *reinterpret_cast<const float4*>(x + (size_t)row * D_ + tid * 4);
  __syncthreads();

  // dt dots: group g (16 threads) computes head g
  {
    const int g = tid >> 4, l = tid & 15;
    float partial = 0.f;
    for (int k = l; k < D_; k += 16) partial += xs[k] * W_dt[k * H_ + g];
    partial += __shfl_xor(partial, 1);
    partial += __shfl_xor(partial, 2);
    partial += __shfl_xor(partial, 4);
    partial += __shfl_xor(partial, 8);
    if (l == 0) {
      float v = partial + b_dt[g];
      float sp = (v > 20.f) ? v : log1pf(expf(v));   // softplus
      gam[g] = expf(-sp);
    }
  }
  __syncthreads();

  // p / gamma_eff / V update; 4 consecutive elems per thread
  const int idx0 = tid * 4;
  const int h = idx0 >> 6;
  float4 pr = *reinterpret_cast<const float4*>(praw + (size_t)row * INNER_ + idx0);
  float p0 = 1.f / (1.f + expf(-(pr.x + b_gsp[idx0 + 0])));
  float p1 = 1.f / (1.f + expf(-(pr.y + b_gsp[idx0 + 1])));
  float p2 = 1.f / (1.f + expf(-(pr.z + b_gsp[idx0 + 2])));
  float p3 = 1.f / (1.f + expf(-(pr.w + b_gsp[idx0 + 3])));
  const float gh = gam[h];
  float lsum = (gh * (1.f - p0) + p0) + (gh * (1.f - p1) + p1) +
               (gh * (1.f - p2) + p2) + (gh * (1.f - p3) + p3);
  float* vp = qkv + ((size_t)row * 3 + 2) * INNER_ + idx0;
  float4 v = *reinterpret_cast<float4*>(vp);
  v.x *= (1.f - p0); v.y *= (1.f - p1); v.z *= (1.f - p2); v.w *= (1.f - p3);
  *reinterpret_cast<float4*>(vp) = v;

  lsum += __shfl_xor(lsum, 1);
  lsum += __shfl_xor(lsum, 2);
  lsum += __shfl_xor(lsum, 4);
  lsum += __shfl_xor(lsum, 8);
  if ((tid & 15) == 0) {
    float gs = lsum * (1.f / 64.f);
    gs = fminf(fmaxf(gs, 1e-6f), 1.f - 1e-6f);
    lg[((size_t)b * H_ + h) * T_ + t] = logf(gs);
  }

  // RoPE on Q and K: this thread's 4 elems = 2 interleaved pairs
  const int j0 = (idx0 & 63) >> 1;     // pair index within head (even)
  float s0, c0, s1, c1;
  sincosf((float)t * inv_freq[j0], &s0, &c0);
  sincosf((float)t * inv_freq[j0 + 1], &s1, &c1);
  float* qp = qkv + (size_t)row * 3 * INNER_ + idx0;   // which=0
  float* kp = qp + INNER_;                             // which=1
  float4 q = *reinterpret_cast<float4*>(qp);
  float4 kk = *reinterpret_cast<float4*>(kp);
  float4 qo, ko;
  qo.x = q.x * c0 - q.y * s0;  qo.y = q.x * s0 + q.y * c0;
  qo.z = q.z * c1 - q.w * s1;  qo.w = q.z * s1 + q.w * c1;
  ko.x = kk.x * c0 - kk.y * s0; ko.y = kk.x * s0 + kk.y * c0;
  ko.z = kk.z * c1 - kk.w * s1; ko.w = kk.z * s1 + kk.w * c1;
  *reinterpret_cast<float4*>(qp) = qo;
  *reinterpret_cast<float4*>(kp) = ko;
}

// ---------------------------------------------------------------------------
// Inclusive prefix sum of lg over T per (b,h). One block per (b,h).
// ---------------------------------------------------------------------------
__global__ __launch_bounds__(256) void scan_kernel(
    const float* __restrict__ lg, float* __restrict__ lgc) {
  const size_t base = (size_t)blockIdx.x * T_;
  const int tid = threadIdx.x;
  __shared__ float sums[256];
  float loc[8];
  float run = 0.f;
#pragma unroll
  for (int i = 0; i < 8; ++i) { run += lg[base + tid * 8 + i]; loc[i] = run; }
  sums[tid] = run;
  __syncthreads();
  if (tid == 0) {
    float r = 0.f;
    for (int i = 0; i < 256; ++i) { float v = sums[i]; sums[i] = r; r += v; }
  }
  __syncthreads();
  const float off = sums[tid];
#pragma unroll
  for (int i = 0; i < 8; ++i) lgc[base + tid * 8 + i] = off + loc[i];
}

// ---------------------------------------------------------------------------
// Causal decay attention, 64x64 tiles, fp32.
// Y[b,t,h*64+dd] = sum_{s<=t} (Q.K^T*SCALE) * exp(clip(lgc_t-lgc_s,-20,0)) * V
// ---------------------------------------------------------------------------
__global__ __launch_bounds__(256) void attn_kernel(
    const float* __restrict__ qkv, const float* __restrict__ lgc,
    float* __restrict__ Y) {
  const int tt = blockIdx.x, h = blockIdx.y, b = blockIdx.z;
  const int tid = threadIdx.x;
  const int tr = tid >> 4, tc = tid & 15;
  __shared__ float Qs[64][65], Ks[64][65], Vs[64][65], Ss[64][65];
  __shared__ float lgt[64], lgs[64];
  const size_t qkvbase = (size_t)b * T_ * 3 * INNER_;
  const size_t lbase = ((size_t)b * H_ + h) * T_;

  for (int e = tid; e < 64 * 64; e += 256) {
    int r = e >> 6, dd = e & 63;
    Qs[r][dd] = qkv[qkvbase + (size_t)(tt * 64 + r) * 3 * INNER_ + h * 64 + dd] * SCALE_;
  }
  if (tid < 64) lgt[tid] = lgc[lbase + tt * 64 + tid];

  float acc[4][4];
#pragma unroll
  for (int i = 0; i < 4; ++i)
#pragma unroll
    for (int j = 0; j < 4; ++j) acc[i][j] = 0.f;

  for (int st = 0; st <= tt; ++st) {
    __syncthreads();   // previous iter done reading Ks/Vs/Ss
    for (int e = tid; e < 64 * 64; e += 256) {
      int r = e >> 6, dd = e & 63;
      size_t rowb = qkvbase + (size_t)(st * 64 + r) * 3 * INNER_ + h * 64 + dd;
      Ks[r][dd] = qkv[rowb + 1 * INNER_];
      Vs[r][dd] = qkv[rowb + 2 * INNER_];
    }
    if (tid < 64) lgs[tid] = lgc[lbase + st * 64 + tid];
    __syncthreads();

    float s[4][4];
#pragma unroll
    for (int i = 0; i < 4; ++i)
#pragma unroll
      for (int j = 0; j < 4; ++j) s[i][j] = 0.f;
    for (int kd = 0; kd < 64; ++kd) {
      float a[4], bb[4];
#pragma unroll
      for (int i = 0; i < 4; ++i) a[i] = Qs[tr * 4 + i][kd];
#pragma unroll
      for (int j = 0; j < 4; ++j) bb[j] = Ks[tc * 4 + j][kd];
#pragma unroll
      for (int i = 0; i < 4; ++i)
#pragma unroll
        for (int j = 0; j < 4; ++j) s[i][j] = fmaf(a[i], bb[j], s[i][j]);
    }
    // decay + causal mask, stage S to LDS
#pragma unroll
    for (int i = 0; i < 4; ++i) {
      const int rl = tr * 4 + i;
      const int rg = tt * 64 + rl;
#pragma unroll
      for (int j = 0; j < 4; ++j) {
        const int cl = tc * 4 + j;
        const int cg = st * 64 + cl;
        float w = 0.f;
        if (cg <= rg) {
          float ld = lgt[rl] - lgs[cl];
          ld = fminf(fmaxf(ld, -20.f), 0.f);
          w = expf(ld);
        }
        Ss[rl][cl] = s[i][j] * w;
      }
    }
    __syncthreads();
    for (int ks = 0; ks < 64; ++ks) {
      float a[4], bb[4];
#pragma unroll
      for (int i = 0; i < 4; ++i) a[i] = Ss[tr * 4 + i][ks];
#pragma unroll
      for (int j = 0; j < 4; ++j) bb[j] = Vs[ks][tc * 4 + j];
#pragma unroll
      for (int i = 0; i < 4; ++i)
#pragma unroll
        for (int j = 0; j < 4; ++j) acc[i][j] = fmaf(a[i], bb[j], acc[i][j]);
    }
  }

#pragma unroll
  for (int i = 0; i < 4; ++i)
#pragma unroll
    for (int j = 0; j < 4; ++j)
      Y[(size_t)(b * T_ + tt * 64 + tr * 4 + i) * INNER_ + h * 64 + tc * 4 + j] =
          acc[i][j];
}

// ---------------------------------------------------------------------------
extern "C" void kernel_launch(void* const* d_in, const int* in_sizes, int n_in,
                              void* d_out, int out_size, void* d_ws, size_t ws_size,
                              hipStream_t stream) {
  const float* x        = (const float*)d_in[0];
  const float* W_qkv    = (const float*)d_in[1];
  const float* W_out    = (const float*)d_in[2];
  const float* W_dt     = (const float*)d_in[3];
  const float* b_dt     = (const float*)d_in[4];
  const float* W_gsp    = (const float*)d_in[5];
  const float* b_gsp    = (const float*)d_in[6];
  const float* inv_freq = (const float*)d_in[7];
  float* out = (float*)d_out;

  const int M = B_ * T_;          // 4096
  float* ws   = (float*)d_ws;
  float* qkvb = ws;                                   // M*3*INNER
  float* praw = qkvb + (size_t)M * 3 * INNER_;        // M*INNER
  float* lg   = praw + (size_t)M * INNER_;            // B*H*T
  float* lgc  = lg + (size_t)B_ * H_ * T_;            // B*H*T
  float* Yb   = lgc + (size_t)B_ * H_ * T_;           // M*INNER

  // 1) qkv = x @ W_qkv   (4096 x 3072 x 1024)
  sgemm128<<<dim3(3 * INNER_ / 128, M / 128), 256, 0, stream>>>(
      x, W_qkv, qkvb, M, 3 * INNER_, D_);
  // 2) praw = x @ W_gsp  (4096 x 1024 x 1024)
  sgemm128<<<dim3(INNER_ / 128, M / 128), 256, 0, stream>>>(
      x, W_gsp, praw, M, INNER_, D_);
  // 3) pointwise: dt/gamma, p, V*(1-p), RoPE, log_gamma
  pointwise_kernel<<<M, 256, 0, stream>>>(x, praw, qkvb, W_dt, b_dt, b_gsp,
                                          inv_freq, lg);
  // 4) cumsum over T per (b,h)
  scan_kernel<<<B_ * H_, 256, 0, stream>>>(lg, lgc);
  // 5) attention
  attn_kernel<<<dim3(T_ / 64, H_, B_), 256, 0, stream>>>(qkvb, lgc, Yb);
  // 6) out = Y @ W_out  (4096 x 1024 x 1024)
  sgemm128<<<dim3(D_ / 128, M / 128), 256, 0, stream>>>(Yb, W_out, out, M, D_, D_);
}

// Round 2
// 277.608 us; speedup vs baseline: 5.3977x; 5.3977x over previous
//
#include <hip/hip_runtime.h>
#include <hip/hip_bf16.h>
#include <math.h>

#define B_     2
#define T_     2048
#define D_     1024
#define H_     16
#define INNER_ 1024
#define SCALE_ 0.125f   // 64^-0.5

typedef unsigned short u16;
typedef short short8 __attribute__((ext_vector_type(8)));
typedef float f32x4 __attribute__((ext_vector_type(4)));
typedef unsigned short u16x4 __attribute__((ext_vector_type(4)));

__device__ __forceinline__ u16 f2bf(float x) {
  union { float f; unsigned u; } v; v.f = x;
  unsigned r = v.u + 0x7fffu + ((v.u >> 16) & 1u);   // RNE, finite inputs
  return (u16)(r >> 16);
}
__device__ __forceinline__ float b2f(u16 x) {
  union { unsigned u; float f; } v; v.u = ((unsigned)x) << 16;
  return v.f;
}
// async global->LDS, 16B per lane; LDS dest = wave-uniform base + lane*16
__device__ __forceinline__ void gload16(const void* g, void* l) {
  __builtin_amdgcn_global_load_lds(
      (const __attribute__((address_space(1))) void*)g,
      (__attribute__((address_space(3))) void*)l, 16, 0, 0);
}

// ---------------------------------------------------------------------------
// casts
// ---------------------------------------------------------------------------
__global__ __launch_bounds__(256) void cast_bf16_kernel(
    const float* __restrict__ src, u16* __restrict__ dst, int n4) {
  int i = blockIdx.x * 256 + threadIdx.x;
  if (i >= n4) return;
  float4 v = *reinterpret_cast<const float4*>(src + (size_t)i * 4);
  u16x4 o; o.x = f2bf(v.x); o.y = f2bf(v.y); o.z = f2bf(v.z); o.w = f2bf(v.w);
  *reinterpret_cast<u16x4*>(dst + (size_t)i * 4) = o;
}

// src [K][N] f32  ->  dst [N][K] bf16
__global__ __launch_bounds__(256) void cast_transpose_kernel(
    const float* __restrict__ src, u16* __restrict__ dst, int K, int N) {
  __shared__ float tile[64][65];
  const int k0 = blockIdx.y * 64, n0 = blockIdx.x * 64;
  for (int e = threadIdx.x; e < 4096; e += 256) {
    int kk = e >> 6, nn = e & 63;
    tile[kk][nn] = src[(size_t)(k0 + kk) * N + n0 + nn];
  }
  __syncthreads();
  for (int e = threadIdx.x; e < 4096; e += 256) {
    int nn = e >> 6, kk = e & 63;
    dst[(size_t)(n0 + nn) * K + k0 + kk] = f2bf(tile[kk][nn]);
  }
}

// ---------------------------------------------------------------------------
// bf16 MFMA GEMM:  C(MxN) = A(MxK) @ Bt(NxK)^T, A/Bt bf16 row-major.
// 128x128 tile, BK=64, 4 waves, 4x4 16x16 acc per wave.
// LDS linear rows of 128B, XOR-swizzle (slot ^= row&7) applied on the global
// source at stage time and on the ds_read address (guide G4 / m201 pattern).
// ---------------------------------------------------------------------------
template <bool BF16OUT>
__global__ __launch_bounds__(256) void gemm_bt(
    const u16* __restrict__ A, const u16* __restrict__ Bt,
    void* __restrict__ Cv, int M, int N, int K) {
  __shared__ u16 As[128 * 64] __attribute__((aligned(16)));
  __shared__ u16 Bs[128 * 64] __attribute__((aligned(16)));
  const int tid = threadIdx.x;
  const int w = tid >> 6, l = tid & 63;
  const int m0 = blockIdx.y * 128, n0 = blockIdx.x * 128;
  const int wr = (w >> 1) * 64, wc = (w & 1) * 64;
  const int srow = l >> 3;                  // row within 8-row chunk
  const int kgrp = ((l & 7) ^ srow) * 8;    // pre-swizzled k offset (elems)

  f32x4 acc[4][4] = {};

  for (int kt = 0; kt < K; kt += 64) {
    if (kt) __syncthreads();
#pragma unroll
    for (int i = 0; i < 4; ++i) {
      int c = w * 4 + i;                    // chunk 0..15 (1KB each)
      int row = c * 8 + srow;
      gload16(A + (size_t)(m0 + row) * K + kt + kgrp, (char*)As + c * 1024);
      gload16(Bt + (size_t)(n0 + row) * K + kt + kgrp, (char*)Bs + c * 1024);
    }
    __syncthreads();
#pragma unroll
    for (int kk = 0; kk < 2; ++kk) {
      short8 af[4], bf[4];
#pragma unroll
      for (int i = 0; i < 4; ++i) {
        int ra = wr + i * 16 + (l & 15);
        int sa = kk * 4 + (l >> 4);
        af[i] = *(const short8*)((const char*)As + ra * 128 + ((sa ^ (ra & 7)) << 4));
        int rb = wc + i * 16 + (l & 15);
        bf[i] = *(const short8*)((const char*)Bs + rb * 128 + ((sa ^ (rb & 7)) << 4));
      }
#pragma unroll
      for (int i = 0; i < 4; ++i)
#pragma unroll
        for (int j = 0; j < 4; ++j)
          acc[i][j] = __builtin_amdgcn_mfma_f32_16x16x32_bf16(af[i], bf[j], acc[i][j], 0, 0, 0);
    }
  }
#pragma unroll
  for (int i = 0; i < 4; ++i) {
#pragma unroll
    for (int r = 0; r < 4; ++r) {
      size_t row = (size_t)(m0 + wr + i * 16 + (l >> 4) * 4 + r);
      size_t base = row * N + n0 + wc + (l & 15);
#pragma unroll
      for (int j = 0; j < 4; ++j) {
        if (BF16OUT) ((u16*)Cv)[base + j * 16] = f2bf(acc[i][j][r]);
        else         ((float*)Cv)[base + j * 16] = acc[i][j][r];
      }
    }
  }
}

// ---------------------------------------------------------------------------
// pointwise: dt/softplus/gamma, p=sigmoid, V*=(1-p), RoPE(Q,K), log_gamma.
// Reads bf16 qkv [M][3072] + bf16 praw; writes head-major bf16 Q/K/V
// [B][H][T][64] and lg [B*H][T] (f32).
// ---------------------------------------------------------------------------
__global__ __launch_bounds__(256) void pointwise_kernel(
    const float* __restrict__ x, const u16* __restrict__ praw,
    const u16* __restrict__ qkv, u16* __restrict__ Qb, u16* __restrict__ Kb,
    u16* __restrict__ Vb, const float* __restrict__ W_dt,
    const float* __restrict__ b_dt, const float* __restrict__ b_gsp,
    const float* __restrict__ inv_freq, float* __restrict__ lg) {
  const int row = blockIdx.x;          // b*T + t
  const int b = row >> 11;
  const int t = row & (T_ - 1);
  const int tid = threadIdx.x;
  __shared__ float xs[D_];
  __shared__ float gam[H_];

  *reinterpret_cast<float4*>(&xs[tid * 4]) =
      *reinterpret_cast<const float4*>(x + (size_t)row * D_ + tid * 4);
  __syncthreads();

  {  // dt dot, head g per 16-lane group
    const int g = tid >> 4, ll = tid & 15;
    float partial = 0.f;
    for (int k = ll; k < D_; k += 16) partial += xs[k] * W_dt[k * H_ + g];
    partial += __shfl_xor(partial, 1);
    partial += __shfl_xor(partial, 2);
    partial += __shfl_xor(partial, 4);
    partial += __shfl_xor(partial, 8);
    if (ll == 0) {
      float v = partial + b_dt[g];
      float sp = (v > 20.f) ? v : log1pf(expf(v));
      gam[g] = expf(-sp);
    }
  }
  __syncthreads();

  const int idx0 = tid * 4;
  const int h = idx0 >> 6;
  const int dd0 = idx0 & 63;
  u16x4 pr = *reinterpret_cast<const u16x4*>(praw + (size_t)row * INNER_ + idx0);
  float p0 = 1.f / (1.f + __expf(-(b2f(pr.x) + b_gsp[idx0 + 0])));
  float p1 = 1.f / (1.f + __expf(-(b2f(pr.y) + b_gsp[idx0 + 1])));
  float p2 = 1.f / (1.f + __expf(-(b2f(pr.z) + b_gsp[idx0 + 2])));
  float p3 = 1.f / (1.f + __expf(-(b2f(pr.w) + b_gsp[idx0 + 3])));
  const float gh = gam[h];
  float lsum = (gh * (1.f - p0) + p0) + (gh * (1.f - p1) + p1) +
               (gh * (1.f - p2) + p2) + (gh * (1.f - p3) + p3);

  const size_t qkvrow = (size_t)row * 3 * INNER_;
  const size_t hm = (((size_t)(b * H_ + h)) * T_ + t) * 64 + dd0;  // head-major

  u16x4 vv = *reinterpret_cast<const u16x4*>(qkv + qkvrow + 2 * INNER_ + idx0);
  u16x4 vo;
  vo.x = f2bf(b2f(vv.x) * (1.f - p0));
  vo.y = f2bf(b2f(vv.y) * (1.f - p1));
  vo.z = f2bf(b2f(vv.z) * (1.f - p2));
  vo.w = f2bf(b2f(vv.w) * (1.f - p3));
  *reinterpret_cast<u16x4*>(Vb + hm) = vo;

  lsum += __shfl_xor(lsum, 1);
  lsum += __shfl_xor(lsum, 2);
  lsum += __shfl_xor(lsum, 4);
  lsum += __shfl_xor(lsum, 8);
  if ((tid & 15) == 0) {
    float gs = lsum * (1.f / 64.f);
    gs = fminf(fmaxf(gs, 1e-6f), 1.f - 1e-6f);
    lg[((size_t)(b * H_ + h)) * T_ + t] = logf(gs);
  }

  // RoPE
  const int j0 = dd0 >> 1;
  float s0, c0, s1, c1;
  sincosf((float)t * inv_freq[j0], &s0, &c0);
  sincosf((float)t * inv_freq[j0 + 1], &s1, &c1);
  u16x4 q = *reinterpret_cast<const u16x4*>(qkv + qkvrow + idx0);
  u16x4 kx = *reinterpret_cast<const u16x4*>(qkv + qkvrow + INNER_ + idx0);
  float qx = b2f(q.x), qy = b2f(q.y), qz = b2f(q.z), qw = b2f(q.w);
  float kxx = b2f(kx.x), kxy = b2f(kx.y), kxz = b2f(kx.z), kxw = b2f(kx.w);
  u16x4 qo, ko;
  qo.x = f2bf(qx * c0 - qy * s0);  qo.y = f2bf(qx * s0 + qy * c0);
  qo.z = f2bf(qz * c1 - qw * s1);  qo.w = f2bf(qz * s1 + qw * c1);
  ko.x = f2bf(kxx * c0 - kxy * s0); ko.y = f2bf(kxx * s0 + kxy * c0);
  ko.z = f2bf(kxz * c1 - kxw * s1); ko.w = f2bf(kxz * s1 + kxw * c1);
  *reinterpret_cast<u16x4*>(Qb + hm) = qo;
  *reinterpret_cast<u16x4*>(Kb + hm) = ko;
}

// ---------------------------------------------------------------------------
// inclusive cumsum over T per (b,h)
// ---------------------------------------------------------------------------
__global__ __launch_bounds__(256) void scan_kernel(
    const float* __restrict__ lg, float* __restrict__ lgc) {
  const size_t base = (size_t)blockIdx.x * T_;
  const int tid = threadIdx.x;
  __shared__ float sums[256];
  float loc[8];
  float run = 0.f;
#pragma unroll
  for (int i = 0; i < 8; ++i) { run += lg[base + tid * 8 + i]; loc[i] = run; }
  sums[tid] = run;
  __syncthreads();
  if (tid == 0) {
    float r = 0.f;
    for (int i = 0; i < 256; ++i) { float v = sums[i]; sums[i] = r; r += v; }
  }
  __syncthreads();
  const float off = sums[tid];
#pragma unroll
  for (int i = 0; i < 8; ++i) lgc[base + tid * 8 + i] = off + loc[i];
}

// ---------------------------------------------------------------------------
// MFMA attention. One block = 64 Q rows of one (b,h). 4 waves; wave w owns
// Q rows w*16..w*16+15 (full 64-dd output). Decay weight applied in fp32
// accumulator; P routed via LDS to bf16 A-frags; V transposed at stage.
// Early break when whole tile decay <= exp(-20) (lgc strictly decreasing).
// ---------------------------------------------------------------------------
__global__ __launch_bounds__(256) void attn_mfma(
    const u16* __restrict__ Qb, const u16* __restrict__ Kb,
    const u16* __restrict__ Vb, const float* __restrict__ lgc,
    u16* __restrict__ Y) {
  const int tt = blockIdx.x, h = blockIdx.y, b = blockIdx.z;
  const int tid = threadIdx.x, w = tid >> 6, l = tid & 63;
  __shared__ u16 Qs[64 * 64] __attribute__((aligned(16)));
  __shared__ u16 Ks[64 * 64] __attribute__((aligned(16)));
  __shared__ u16 Vt[64 * 72] __attribute__((aligned(16)));   // [dd][s] pad->72
  __shared__ u16 Ps[64 * 72] __attribute__((aligned(16)));   // [qrow][s]
  const size_t bh = (size_t)b * H_ + h;
  const size_t qkbase = bh * T_ * 64;
  const float* lgp = lgc + bh * T_;

  const int srow = l >> 3;
  const int kgrp = ((l & 7) ^ srow) * 8;

#pragma unroll
  for (int i = 0; i < 2; ++i) {   // stage Q (8 chunks)
    int c = w * 2 + i;
    int row = c * 8 + srow;
    gload16(Qb + qkbase + (size_t)(tt * 64 + row) * 64 + kgrp, (char*)Qs + c * 1024);
  }
  float lgt[4];
#pragma unroll
  for (int r = 0; r < 4; ++r) lgt[r] = lgp[tt * 64 + w * 16 + (l >> 4) * 4 + r];
  const float lgtop = lgp[tt * 64];
  __syncthreads();

  short8 qf[2];
#pragma unroll
  for (int kk = 0; kk < 2; ++kk) {
    int row = w * 16 + (l & 15);
    int slot = kk * 4 + (l >> 4);
    qf[kk] = *(const short8*)((const char*)Qs + row * 128 + ((slot ^ (row & 7)) << 4));
  }

  f32x4 yacc[4] = {};

  for (int st = tt; st >= 0; --st) {
    if (st < tt && lgtop - lgp[st * 64 + 63] <= -20.f) break;  // decay window
    __syncthreads();   // prev iter done reading Ks/Vt/Ps
#pragma unroll
    for (int i = 0; i < 2; ++i) {   // stage K
      int c = w * 2 + i;
      int row = c * 8 + srow;
      gload16(Kb + qkbase + (size_t)(st * 64 + row) * 64 + kgrp, (char*)Ks + c * 1024);
    }
    {  // stage V transposed: thread -> (vrow = tid&63, d0 = (tid>>6)*16)
      int vrow = tid & 63;
      int d0 = (tid >> 6) * 16;
      const u16* vp = Vb + qkbase + (size_t)(st * 64 + vrow) * 64 + d0;
      short8 v0 = *(const short8*)(vp);
      short8 v1 = *(const short8*)(vp + 8);
#pragma unroll
      for (int j = 0; j < 8; ++j) {
        Vt[(d0 + j) * 72 + vrow] = (u16)v0[j];
        Vt[(d0 + 8 + j) * 72 + vrow] = (u16)v1[j];
      }
    }
    float lgs4[4];
#pragma unroll
    for (int n = 0; n < 4; ++n) lgs4[n] = lgp[st * 64 + n * 16 + (l & 15)];
    __syncthreads();

    const bool diag = (st == tt);
#pragma unroll
    for (int n = 0; n < 4; ++n) {
      f32x4 s = {};
#pragma unroll
      for (int kk = 0; kk < 2; ++kk) {
        int row = n * 16 + (l & 15);
        int slot = kk * 4 + (l >> 4);
        short8 kf = *(const short8*)((const char*)Ks + row * 128 + ((slot ^ (row & 7)) << 4));
        s = __builtin_amdgcn_mfma_f32_16x16x32_bf16(qf[kk], kf, s, 0, 0, 0);
      }
      const int coll = n * 16 + (l & 15);
#pragma unroll
      for (int r = 0; r < 4; ++r) {
        int rowl = w * 16 + (l >> 4) * 4 + r;
        float ld = lgt[r] - lgs4[n];
        ld = fminf(fmaxf(ld, -20.f), 0.f);
        float pv = s[r] * (SCALE_ * __expf(ld));
        if (diag && coll > rowl) pv = 0.f;
        Ps[rowl * 72 + coll] = f2bf(pv);
      }
    }
    __syncthreads();
#pragma unroll
    for (int kk = 0; kk < 2; ++kk) {
      int prow = w * 16 + (l & 15);
      short8 pf = *(const short8*)((const char*)Ps + prow * 144 + (kk * 32 + (l >> 4) * 8) * 2);
#pragma unroll
      for (int n2 = 0; n2 < 4; ++n2) {
        short8 vf = *(const short8*)((const char*)Vt + (n2 * 16 + (l & 15)) * 144 + (kk * 32 + (l >> 4) * 8) * 2);
        yacc[n2] = __builtin_amdgcn_mfma_f32_16x16x32_bf16(pf, vf, yacc[n2], 0, 0, 0);
      }
    }
  }

#pragma unroll
  for (int n2 = 0; n2 < 4; ++n2)
#pragma unroll
    for (int r = 0; r < 4; ++r) {
      size_t row = (size_t)(b * T_) + tt * 64 + w * 16 + (l >> 4) * 4 + r;
      Y[row * INNER_ + h * 64 + n2 * 16 + (l & 15)] = f2bf(yacc[n2][r]);
    }
}

// ---------------------------------------------------------------------------
extern "C" void kernel_launch(void* const* d_in, const int* in_sizes, int n_in,
                              void* d_out, int out_size, void* d_ws, size_t ws_size,
                              hipStream_t stream) {
  const float* x        = (const float*)d_in[0];
  const float* W_qkv    = (const float*)d_in[1];
  const float* W_out    = (const float*)d_in[2];
  const float* W_dt     = (const float*)d_in[3];
  const float* b_dt     = (const float*)d_in[4];
  const float* W_gsp    = (const float*)d_in[5];
  const float* b_gsp    = (const float*)d_in[6];
  const float* inv_freq = (const float*)d_in[7];
  float* out = (float*)d_out;

  const int M = B_ * T_;  // 4096
  char* p = (char*)d_ws;
  auto alloc = [&](size_t bytes) {
    char* r = p; p += (bytes + 255) & ~(size_t)255; return r;
  };
  u16*   xb    = (u16*)alloc((size_t)M * D_ * 2);            // 8 MB
  u16*   Wqkvt = (u16*)alloc((size_t)3 * INNER_ * D_ * 2);   // 6 MB  [N][K]
  u16*   Wgspt = (u16*)alloc((size_t)INNER_ * D_ * 2);       // 2 MB
  u16*   Woutt = (u16*)alloc((size_t)D_ * INNER_ * 2);       // 2 MB
  u16*   qkvb  = (u16*)alloc((size_t)M * 3 * INNER_ * 2);    // 24 MB
  u16*   prawb = (u16*)alloc((size_t)M * INNER_ * 2);        // 8 MB
  u16*   Qb    = (u16*)alloc((size_t)B_ * H_ * T_ * 64 * 2); // 8 MB
  u16*   Kb    = (u16*)alloc((size_t)B_ * H_ * T_ * 64 * 2);
  u16*   Vb    = (u16*)alloc((size_t)B_ * H_ * T_ * 64 * 2);
  u16*   Yb    = (u16*)alloc((size_t)M * INNER_ * 2);        // 8 MB
  float* lg    = (float*)alloc((size_t)B_ * H_ * T_ * 4);
  float* lgc   = (float*)alloc((size_t)B_ * H_ * T_ * 4);

  // casts / transposes
  cast_bf16_kernel<<<(M * D_ / 4 + 255) / 256, 256, 0, stream>>>(x, xb, M * D_ / 4);
  cast_transpose_kernel<<<dim3(3 * INNER_ / 64, D_ / 64), 256, 0, stream>>>(
      W_qkv, Wqkvt, D_, 3 * INNER_);
  cast_transpose_kernel<<<dim3(INNER_ / 64, D_ / 64), 256, 0, stream>>>(
      W_gsp, Wgspt, D_, INNER_);
  cast_transpose_kernel<<<dim3(D_ / 64, INNER_ / 64), 256, 0, stream>>>(
      W_out, Woutt, INNER_, D_);

  // qkv = x @ W_qkv ; praw = x @ W_gsp   (bf16 out)
  gemm_bt<true><<<dim3(3 * INNER_ / 128, M / 128), 256, 0, stream>>>(
      xb, Wqkvt, qkvb, M, 3 * INNER_, D_);
  gemm_bt<true><<<dim3(INNER_ / 128, M / 128), 256, 0, stream>>>(
      xb, Wgspt, prawb, M, INNER_, D_);

  pointwise_kernel<<<M, 256, 0, stream>>>(x, prawb, qkvb, Qb, Kb, Vb, W_dt,
                                          b_dt, b_gsp, inv_freq, lg);
  scan_kernel<<<B_ * H_, 256, 0, stream>>>(lg, lgc);

  attn_mfma<<<dim3(T_ / 64, H_, B_), 256, 0, stream>>>(Qb, Kb, Vb, lgc, Yb);

  // out = Y @ W_out  (fp32 out)
  gemm_bt<false><<<dim3(D_ / 128, M / 128), 256, 0, stream>>>(
      Yb, Woutt, out, M, D_, INNER_);
}

// Round 3
// 192.761 us; speedup vs baseline: 7.7737x; 1.4402x over previous
//
#include <hip/hip_runtime.h>
#include <hip/hip_bf16.h>
#include <math.h>

#define B_     2
#define T_     2048
#define D_     1024
#define H_     16
#define INNER_ 1024
#define SCALE_ 0.125f   // 64^-0.5

typedef unsigned short u16;
typedef short short8 __attribute__((ext_vector_type(8)));
typedef float f32x4 __attribute__((ext_vector_type(4)));
typedef unsigned short u16x4 __attribute__((ext_vector_type(4)));

__device__ __forceinline__ u16 f2bf(float x) {
  union { float f; unsigned u; } v; v.f = x;
  unsigned r = v.u + 0x7fffu + ((v.u >> 16) & 1u);   // RNE, finite inputs
  return (u16)(r >> 16);
}
__device__ __forceinline__ float b2f(u16 x) {
  union { unsigned u; float f; } v; v.u = ((unsigned)x) << 16;
  return v.f;
}
// async global->LDS, 16B per lane; LDS dest = wave-uniform base + lane*16
__device__ __forceinline__ void gload16(const void* g, void* l) {
  __builtin_amdgcn_global_load_lds(
      (const __attribute__((address_space(1))) void*)g,
      (__attribute__((address_space(3))) void*)l, 16, 0, 0);
}

// ---------------------------------------------------------------------------
// small prep kernels
// ---------------------------------------------------------------------------
__global__ __launch_bounds__(256) void cast_bf16_kernel(
    const float* __restrict__ src, u16* __restrict__ dst, int n4) {
  int i = blockIdx.x * 256 + threadIdx.x;
  if (i >= n4) return;
  float4 v = *reinterpret_cast<const float4*>(src + (size_t)i * 4);
  u16x4 o; o.x = f2bf(v.x); o.y = f2bf(v.y); o.z = f2bf(v.z); o.w = f2bf(v.w);
  *reinterpret_cast<u16x4*>(dst + (size_t)i * 4) = o;
}

// src [K][N] f32  ->  dst [N][K] bf16
__global__ __launch_bounds__(256) void cast_transpose_kernel(
    const float* __restrict__ src, u16* __restrict__ dst, int K, int N) {
  __shared__ float tile[64][65];
  const int k0 = blockIdx.y * 64, n0 = blockIdx.x * 64;
  for (int e = threadIdx.x; e < 4096; e += 256) {
    int kk = e >> 6, nn = e & 63;
    tile[kk][nn] = src[(size_t)(k0 + kk) * N + n0 + nn];
  }
  __syncthreads();
  for (int e = threadIdx.x; e < 4096; e += 256) {
    int nn = e >> 6, kk = e & 63;
    dst[(size_t)(n0 + nn) * K + k0 + kk] = f2bf(tile[kk][nn]);
  }
}

// W_dt [1024][16] f32 -> Wdtt [16][1024] bf16
__global__ __launch_bounds__(256) void wdt_transpose_kernel(
    const float* __restrict__ W_dt, u16* __restrict__ Wdtt) {
  int i = blockIdx.x * 256 + threadIdx.x;  // 16384
  int k = i >> 4, h = i & 15;
  Wdtt[h * D_ + k] = f2bf(W_dt[i]);
}

// RoPE table: tab[t*32+j] = (cos(t*invf[j]), sin(t*invf[j]))
__global__ __launch_bounds__(256) void rope_tab_kernel(
    const float* __restrict__ inv_freq, float2* __restrict__ tab) {
  int i = blockIdx.x * 256 + threadIdx.x;  // 65536
  int t = i >> 5, j = i & 31;
  float s, c;
  sincosf((float)t * inv_freq[j], &s, &c);
  tab[i] = make_float2(c, s);
}

// gam[row][h] = exp(-softplus(x_row . W_dt[:,h] + b_dt[h]))
// wave per row; 4 lanes per head, 256 k-elems per lane.
__global__ __launch_bounds__(256) void gamma_kernel(
    const u16* __restrict__ xb, const u16* __restrict__ Wdtt,
    const float* __restrict__ b_dt, float* __restrict__ gam) {
  const int row = blockIdx.x * 4 + (threadIdx.x >> 6);
  const int l = threadIdx.x & 63;
  const int h = l >> 2;
  const int kc = (l & 3) * 256;
  const short8* xp = (const short8*)(xb + (size_t)row * D_ + kc);
  const short8* wp = (const short8*)(Wdtt + h * D_ + kc);
  float s = 0.f;
#pragma unroll
  for (int i = 0; i < 32; ++i) {
    short8 xv = xp[i], wv = wp[i];
#pragma unroll
    for (int j = 0; j < 8; ++j) s += b2f((u16)xv[j]) * b2f((u16)wv[j]);
  }
  s += __shfl_xor(s, 1);
  s += __shfl_xor(s, 2);
  if ((l & 3) == 0) {
    float v = s + b_dt[h];
    float sp = (v > 20.f) ? v : log1pf(__expf(v));
    gam[row * H_ + h] = __expf(-sp);
  }
}

// ---------------------------------------------------------------------------
// bf16 MFMA GEMM:  C(MxN) = A(MxK) @ Bt(NxK)^T, A/Bt bf16 row-major.
// 128x128 tile, BK=64, 4 waves, 4x4 16x16 acc per wave. global_load_lds w=16,
// source pre-swizzled, ds_read XOR-swizzled (m201 pattern).
// ---------------------------------------------------------------------------
template <bool BF16OUT>
__global__ __launch_bounds__(256) void gemm_bt(
    const u16* __restrict__ A, const u16* __restrict__ Bt,
    void* __restrict__ Cv, int M, int N, int K) {
  __shared__ u16 As[128 * 64] __attribute__((aligned(16)));
  __shared__ u16 Bs[128 * 64] __attribute__((aligned(16)));
  const int tid = threadIdx.x;
  const int w = tid >> 6, l = tid & 63;
  const int m0 = blockIdx.y * 128, n0 = blockIdx.x * 128;
  const int wr = (w >> 1) * 64, wc = (w & 1) * 64;
  const int srow = l >> 3;                  // row within 8-row chunk
  const int kgrp = ((l & 7) ^ srow) * 8;    // pre-swizzled k offset (elems)

  f32x4 acc[4][4] = {};

  for (int kt = 0; kt < K; kt += 64) {
    if (kt) __syncthreads();
#pragma unroll
    for (int i = 0; i < 4; ++i) {
      int c = w * 4 + i;                    // chunk 0..15 (1KB each)
      int row = c * 8 + srow;
      gload16(A + (size_t)(m0 + row) * K + kt + kgrp, (char*)As + c * 1024);
      gload16(Bt + (size_t)(n0 + row) * K + kt + kgrp, (char*)Bs + c * 1024);
    }
    __syncthreads();
#pragma unroll
    for (int kk = 0; kk < 2; ++kk) {
      short8 af[4], bf[4];
#pragma unroll
      for (int i = 0; i < 4; ++i) {
        int ra = wr + i * 16 + (l & 15);
        int sa = kk * 4 + (l >> 4);
        af[i] = *(const short8*)((const char*)As + ra * 128 + ((sa ^ (ra & 7)) << 4));
        int rb = wc + i * 16 + (l & 15);
        bf[i] = *(const short8*)((const char*)Bs + rb * 128 + ((sa ^ (rb & 7)) << 4));
      }
#pragma unroll
      for (int i = 0; i < 4; ++i)
#pragma unroll
        for (int j = 0; j < 4; ++j)
          acc[i][j] = __builtin_amdgcn_mfma_f32_16x16x32_bf16(af[i], bf[j], acc[i][j], 0, 0, 0);
    }
  }
#pragma unroll
  for (int i = 0; i < 4; ++i) {
#pragma unroll
    for (int r = 0; r < 4; ++r) {
      size_t row = (size_t)(m0 + wr + i * 16 + (l >> 4) * 4 + r);
      size_t base = row * N + n0 + wc + (l & 15);
#pragma unroll
      for (int j = 0; j < 4; ++j) {
        if (BF16OUT) ((u16*)Cv)[base + j * 16] = f2bf(acc[i][j][r]);
        else         ((float*)Cv)[base + j * 16] = acc[i][j][r];
      }
    }
  }
}

// ---------------------------------------------------------------------------
// streaming pointwise: reads combined C [M][4096] (q|k|v|praw), gam, rope tab.
// Writes head-major bf16 Q/K/V [B*H][T][64] + lg. Wave per row, 16 elems/lane.
// ---------------------------------------------------------------------------
__global__ __launch_bounds__(256) void pointwise_kernel(
    const u16* __restrict__ C, const float* __restrict__ gam,
    const float* __restrict__ b_gsp, const float2* __restrict__ tab,
    u16* __restrict__ Qb, u16* __restrict__ Kb, u16* __restrict__ Vb,
    float* __restrict__ lg) {
  const int row = blockIdx.x * 4 + (threadIdx.x >> 6);
  const int l = threadIdx.x & 63;
  const int b = row >> 11, t = row & (T_ - 1);
  const int h = l >> 2;
  const int dd0 = (l & 3) * 16;
  const int col = h * 64 + dd0;
  const size_t cb = (size_t)row * 4096;

  const short8* qp = (const short8*)(C + cb + col);
  const short8* kp = (const short8*)(C + cb + 1024 + col);
  const short8* vp = (const short8*)(C + cb + 2048 + col);
  const short8* pp = (const short8*)(C + cb + 3072 + col);
  short8 q0 = qp[0], q1 = qp[1];
  short8 k0 = kp[0], k1 = kp[1];
  short8 v0 = vp[0], v1 = vp[1];
  short8 pr0 = pp[0], pr1 = pp[1];
  const float gh = gam[row * H_ + h];

  float ge = 0.f;
  short8 vo0, vo1;
#pragma unroll
  for (int i = 0; i < 8; ++i) {
    float pv = b2f((u16)pr0[i]) + b_gsp[col + i];
    float p = 1.f / (1.f + __expf(-pv));
    ge += gh * (1.f - p) + p;
    vo0[i] = (short)f2bf(b2f((u16)v0[i]) * (1.f - p));
    float pv1 = b2f((u16)pr1[i]) + b_gsp[col + 8 + i];
    float p1 = 1.f / (1.f + __expf(-pv1));
    ge += gh * (1.f - p1) + p1;
    vo1[i] = (short)f2bf(b2f((u16)v1[i]) * (1.f - p1));
  }
  const size_t hm = (((size_t)(b * H_ + h)) * T_ + t) * 64 + dd0;
  ((short8*)(Vb + hm))[0] = vo0;
  ((short8*)(Vb + hm))[1] = vo1;

  ge += __shfl_xor(ge, 1);
  ge += __shfl_xor(ge, 2);
  if ((l & 3) == 0) {
    float gs = ge * (1.f / 64.f);
    gs = fminf(fmaxf(gs, 1e-6f), 1.f - 1e-6f);
    lg[((size_t)(b * H_ + h)) * T_ + t] = logf(gs);
  }

  // RoPE via table
  short8 qo0, qo1, ko0, ko1;
  const float2* cs = tab + t * 32 + (dd0 >> 1);
#pragma unroll
  for (int m = 0; m < 4; ++m) {
    float2 c0 = cs[m];
    float qa = b2f((u16)q0[2 * m]), qb = b2f((u16)q0[2 * m + 1]);
    qo0[2 * m]     = (short)f2bf(qa * c0.x - qb * c0.y);
    qo0[2 * m + 1] = (short)f2bf(qa * c0.y + qb * c0.x);
    float ka = b2f((u16)k0[2 * m]), kb = b2f((u16)k0[2 * m + 1]);
    ko0[2 * m]     = (short)f2bf(ka * c0.x - kb * c0.y);
    ko0[2 * m + 1] = (short)f2bf(ka * c0.y + kb * c0.x);
    float2 c1 = cs[4 + m];
    float qa1 = b2f((u16)q1[2 * m]), qb1 = b2f((u16)q1[2 * m + 1]);
    qo1[2 * m]     = (short)f2bf(qa1 * c1.x - qb1 * c1.y);
    qo1[2 * m + 1] = (short)f2bf(qa1 * c1.y + qb1 * c1.x);
    float ka1 = b2f((u16)k1[2 * m]), kb1 = b2f((u16)k1[2 * m + 1]);
    ko1[2 * m]     = (short)f2bf(ka1 * c1.x - kb1 * c1.y);
    ko1[2 * m + 1] = (short)f2bf(ka1 * c1.y + kb1 * c1.x);
  }
  ((short8*)(Qb + hm))[0] = qo0; ((short8*)(Qb + hm))[1] = qo1;
  ((short8*)(Kb + hm))[0] = ko0; ((short8*)(Kb + hm))[1] = ko1;
}

// ---------------------------------------------------------------------------
// inclusive cumsum over T per (b,h)
// ---------------------------------------------------------------------------
__global__ __launch_bounds__(256) void scan_kernel(
    const float* __restrict__ lg, float* __restrict__ lgc) {
  const size_t base = (size_t)blockIdx.x * T_;
  const int tid = threadIdx.x;
  __shared__ float sums[256];
  float loc[8];
  float run = 0.f;
#pragma unroll
  for (int i = 0; i < 8; ++i) { run += lg[base + tid * 8 + i]; loc[i] = run; }
  sums[tid] = run;
  __syncthreads();
  if (tid == 0) {
    float r = 0.f;
    for (int i = 0; i < 256; ++i) { float v = sums[i]; sums[i] = r; r += v; }
  }
  __syncthreads();
  const float off = sums[tid];
#pragma unroll
  for (int i = 0; i < 8; ++i) lgc[base + tid * 8 + i] = off + loc[i];
}

// ---------------------------------------------------------------------------
// MFMA attention. One block = 64 Q rows of one (b,h). Decay in fp32 acc;
// P via LDS to bf16 A-frags; V transposed at stage; decay-window early break.
// ---------------------------------------------------------------------------
__global__ __launch_bounds__(256) void attn_mfma(
    const u16* __restrict__ Qb, const u16* __restrict__ Kb,
    const u16* __restrict__ Vb, const float* __restrict__ lgc,
    u16* __restrict__ Y) {
  const int tt = blockIdx.x, h = blockIdx.y, b = blockIdx.z;
  const int tid = threadIdx.x, w = tid >> 6, l = tid & 63;
  __shared__ u16 Qs[64 * 64] __attribute__((aligned(16)));
  __shared__ u16 Ks[64 * 64] __attribute__((aligned(16)));
  __shared__ u16 Vt[64 * 72] __attribute__((aligned(16)));   // [dd][s] pad->72
  __shared__ u16 Ps[64 * 72] __attribute__((aligned(16)));   // [qrow][s]
  const size_t bh = (size_t)b * H_ + h;
  const size_t qkbase = bh * T_ * 64;
  const float* lgp = lgc + bh * T_;

  const int srow = l >> 3;
  const int kgrp = ((l & 7) ^ srow) * 8;

#pragma unroll
  for (int i = 0; i < 2; ++i) {   // stage Q (8 chunks)
    int c = w * 2 + i;
    int row = c * 8 + srow;
    gload16(Qb + qkbase + (size_t)(tt * 64 + row) * 64 + kgrp, (char*)Qs + c * 1024);
  }
  float lgt[4];
#pragma unroll
  for (int r = 0; r < 4; ++r) lgt[r] = lgp[tt * 64 + w * 16 + (l >> 4) * 4 + r];
  const float lgtop = lgp[tt * 64];
  __syncthreads();

  short8 qf[2];
#pragma unroll
  for (int kk = 0; kk < 2; ++kk) {
    int row = w * 16 + (l & 15);
    int slot = kk * 4 + (l >> 4);
    qf[kk] = *(const short8*)((const char*)Qs + row * 128 + ((slot ^ (row & 7)) << 4));
  }

  f32x4 yacc[4] = {};

  for (int st = tt; st >= 0; --st) {
    if (st < tt && lgtop - lgp[st * 64 + 63] <= -20.f) break;  // decay window
    __syncthreads();   // prev iter done reading Ks/Vt/Ps
#pragma unroll
    for (int i = 0; i < 2; ++i) {   // stage K
      int c = w * 2 + i;
      int row = c * 8 + srow;
      gload16(Kb + qkbase + (size_t)(st * 64 + row) * 64 + kgrp, (char*)Ks + c * 1024);
    }
    {  // stage V transposed
      int vrow = tid & 63;
      int d0 = (tid >> 6) * 16;
      const u16* vp = Vb + qkbase + (size_t)(st * 64 + vrow) * 64 + d0;
      short8 v0 = *(const short8*)(vp);
      short8 v1 = *(const short8*)(vp + 8);
#pragma unroll
      for (int j = 0; j < 8; ++j) {
        Vt[(d0 + j) * 72 + vrow] = (u16)v0[j];
        Vt[(d0 + 8 + j) * 72 + vrow] = (u16)v1[j];
      }
    }
    float lgs4[4];
#pragma unroll
    for (int n = 0; n < 4; ++n) lgs4[n] = lgp[st * 64 + n * 16 + (l & 15)];
    __syncthreads();

    const bool diag = (st == tt);
#pragma unroll
    for (int n = 0; n < 4; ++n) {
      f32x4 s = {};
#pragma unroll
      for (int kk = 0; kk < 2; ++kk) {
        int row = n * 16 + (l & 15);
        int slot = kk * 4 + (l >> 4);
        short8 kf = *(const short8*)((const char*)Ks + row * 128 + ((slot ^ (row & 7)) << 4));
        s = __builtin_amdgcn_mfma_f32_16x16x32_bf16(qf[kk], kf, s, 0, 0, 0);
      }
      const int coll = n * 16 + (l & 15);
#pragma unroll
      for (int r = 0; r < 4; ++r) {
        int rowl = w * 16 + (l >> 4) * 4 + r;
        float ld = lgt[r] - lgs4[n];
        ld = fminf(fmaxf(ld, -20.f), 0.f);
        float pv = s[r] * (SCALE_ * __expf(ld));
        if (diag && coll > rowl) pv = 0.f;
        Ps[rowl * 72 + coll] = f2bf(pv);
      }
    }
    __syncthreads();
#pragma unroll
    for (int kk = 0; kk < 2; ++kk) {
      int prow = w * 16 + (l & 15);
      short8 pf = *(const short8*)((const char*)Ps + prow * 144 + (kk * 32 + (l >> 4) * 8) * 2);
#pragma unroll
      for (int n2 = 0; n2 < 4; ++n2) {
        short8 vf = *(const short8*)((const char*)Vt + (n2 * 16 + (l & 15)) * 144 + (kk * 32 + (l >> 4) * 8) * 2);
        yacc[n2] = __builtin_amdgcn_mfma_f32_16x16x32_bf16(pf, vf, yacc[n2], 0, 0, 0);
      }
    }
  }

#pragma unroll
  for (int n2 = 0; n2 < 4; ++n2)
#pragma unroll
    for (int r = 0; r < 4; ++r) {
      size_t row = (size_t)(b * T_) + tt * 64 + w * 16 + (l >> 4) * 4 + r;
      Y[row * INNER_ + h * 64 + n2 * 16 + (l & 15)] = f2bf(yacc[n2][r]);
    }
}

// ---------------------------------------------------------------------------
extern "C" void kernel_launch(void* const* d_in, const int* in_sizes, int n_in,
                              void* d_out, int out_size, void* d_ws, size_t ws_size,
                              hipStream_t stream) {
  const float* x        = (const float*)d_in[0];
  const float* W_qkv    = (const float*)d_in[1];
  const float* W_out    = (const float*)d_in[2];
  const float* W_dt     = (const float*)d_in[3];
  const float* b_dt     = (const float*)d_in[4];
  const float* W_gsp    = (const float*)d_in[5];
  const float* b_gsp    = (const float*)d_in[6];
  const float* inv_freq = (const float*)d_in[7];
  float* out = (float*)d_out;

  const int M = B_ * T_;  // 4096
  char* p = (char*)d_ws;
  auto alloc = [&](size_t bytes) {
    char* r = p; p += (bytes + 255) & ~(size_t)255; return r;
  };
  u16*    xb    = (u16*)alloc((size_t)M * D_ * 2);             // 8 MB
  u16*    Wcombt= (u16*)alloc((size_t)4096 * D_ * 2);          // 8 MB [N=4096][K]
  u16*    Woutt = (u16*)alloc((size_t)D_ * INNER_ * 2);        // 2 MB
  u16*    Wdtt  = (u16*)alloc((size_t)H_ * D_ * 2);            // 32 KB
  u16*    Cqkvp = (u16*)alloc((size_t)M * 4096 * 2);           // 32 MB
  u16*    Qb    = (u16*)alloc((size_t)B_ * H_ * T_ * 64 * 2);  // 8 MB
  u16*    Kb    = (u16*)alloc((size_t)B_ * H_ * T_ * 64 * 2);
  u16*    Vb    = (u16*)alloc((size_t)B_ * H_ * T_ * 64 * 2);
  u16*    Yb    = (u16*)alloc((size_t)M * INNER_ * 2);         // 8 MB
  float*  gam   = (float*)alloc((size_t)M * H_ * 4);           // 256 KB
  float*  lg    = (float*)alloc((size_t)B_ * H_ * T_ * 4);
  float*  lgc   = (float*)alloc((size_t)B_ * H_ * T_ * 4);
  float2* tab   = (float2*)alloc((size_t)T_ * 32 * 8);         // 512 KB

  // prep
  cast_bf16_kernel<<<(M * D_ / 4 + 255) / 256, 256, 0, stream>>>(x, xb, M * D_ / 4);
  wdt_transpose_kernel<<<64, 256, 0, stream>>>(W_dt, Wdtt);
  rope_tab_kernel<<<T_ * 32 / 256, 256, 0, stream>>>(inv_freq, tab);
  cast_transpose_kernel<<<dim3(3 * INNER_ / 64, D_ / 64), 256, 0, stream>>>(
      W_qkv, Wcombt, D_, 3 * INNER_);
  cast_transpose_kernel<<<dim3(INNER_ / 64, D_ / 64), 256, 0, stream>>>(
      W_gsp, Wcombt + (size_t)3 * INNER_ * D_, D_, INNER_);
  cast_transpose_kernel<<<dim3(D_ / 64, INNER_ / 64), 256, 0, stream>>>(
      W_out, Woutt, INNER_, D_);

  // combined projection GEMM: [q|k|v|praw] = x @ [W_qkv|W_gsp]  (N=4096)
  gemm_bt<true><<<dim3(4096 / 128, M / 128), 256, 0, stream>>>(
      xb, Wcombt, Cqkvp, M, 4096, D_);

  // gamma (dt matvec) + streaming pointwise
  gamma_kernel<<<M / 4, 256, 0, stream>>>(xb, Wdtt, b_dt, gam);
  pointwise_kernel<<<M / 4, 256, 0, stream>>>(Cqkvp, gam, b_gsp, tab,
                                              Qb, Kb, Vb, lg);
  scan_kernel<<<B_ * H_, 256, 0, stream>>>(lg, lgc);

  attn_mfma<<<dim3(T_ / 64, H_, B_), 256, 0, stream>>>(Qb, Kb, Vb, lgc, Yb);

  // out = Y @ W_out  (fp32 out)
  gemm_bt<false><<<dim3(D_ / 128, M / 128), 256, 0, stream>>>(
      Yb, Woutt, out, M, D_, INNER_);
}

// Round 4
// 156.553 us; speedup vs baseline: 9.5716x; 1.2313x over previous
//
#include <hip/hip_runtime.h>
#include <hip/hip_bf16.h>
#include <math.h>

#define B_     2
#define T_     2048
#define D_     1024
#define H_     16
#define INNER_ 1024
#define NC_    4224       // combined GEMM N: 3072 qkv + 1024 gsp + 128 (dt pad)
#define SCALE_ 0.125f     // 64^-0.5, folded into Q at pointwise

typedef unsigned short u16;
typedef short short8 __attribute__((ext_vector_type(8)));
typedef float f32x4 __attribute__((ext_vector_type(4)));
typedef unsigned short u16x4 __attribute__((ext_vector_type(4)));

__device__ __forceinline__ u16 f2bf(float x) {
  union { float f; unsigned u; } v; v.f = x;
  unsigned r = v.u + 0x7fffu + ((v.u >> 16) & 1u);   // RNE, finite inputs
  return (u16)(r >> 16);
}
__device__ __forceinline__ float b2f(u16 x) {
  union { unsigned u; float f; } v; v.u = ((unsigned)x) << 16;
  return v.f;
}
// async global->LDS, 16B per lane; LDS dest = wave-uniform base + lane*16
__device__ __forceinline__ void gload16(const void* g, void* l) {
  __builtin_amdgcn_global_load_lds(
      (const __attribute__((address_space(1))) void*)g,
      (__attribute__((address_space(3))) void*)l, 16, 0, 0);
}

// ---------------------------------------------------------------------------
// prep kernels
// ---------------------------------------------------------------------------
__global__ __launch_bounds__(256) void cast_bf16_kernel(
    const float* __restrict__ src, u16* __restrict__ dst, int n4) {
  int i = blockIdx.x * 256 + threadIdx.x;
  if (i >= n4) return;
  float4 v = *reinterpret_cast<const float4*>(src + (size_t)i * 4);
  u16x4 o; o.x = f2bf(v.x); o.y = f2bf(v.y); o.z = f2bf(v.z); o.w = f2bf(v.w);
  *reinterpret_cast<u16x4*>(dst + (size_t)i * 4) = o;
}

// src [K][N] f32  ->  dst [N][K] bf16
__global__ __launch_bounds__(256) void cast_transpose_kernel(
    const float* __restrict__ src, u16* __restrict__ dst, int K, int N) {
  __shared__ float tile[64][65];
  const int k0 = blockIdx.y * 64, n0 = blockIdx.x * 64;
  for (int e = threadIdx.x; e < 4096; e += 256) {
    int kk = e >> 6, nn = e & 63;
    tile[kk][nn] = src[(size_t)(k0 + kk) * N + n0 + nn];
  }
  __syncthreads();
  for (int e = threadIdx.x; e < 4096; e += 256) {
    int nn = e >> 6, kk = e & 63;
    dst[(size_t)(n0 + nn) * K + k0 + kk] = f2bf(tile[kk][nn]);
  }
}

// W_dt [1024][16] f32 -> rows 4096..4111 of Wcombt ([h][k] bf16)
__global__ __launch_bounds__(256) void wdt_transpose_kernel(
    const float* __restrict__ W_dt, u16* __restrict__ dst) {
  int i = blockIdx.x * 256 + threadIdx.x;  // 16384
  int k = i >> 4, h = i & 15;
  dst[(size_t)h * D_ + k] = f2bf(W_dt[i]);
}

// RoPE table: tab[t*32+j] = (cos(t*invf[j]), sin(t*invf[j]))
__global__ __launch_bounds__(256) void rope_tab_kernel(
    const float* __restrict__ inv_freq, float2* __restrict__ tab) {
  int i = blockIdx.x * 256 + threadIdx.x;  // 65536
  int t = i >> 5, j = i & 31;
  float s, c;
  sincosf((float)t * inv_freq[j], &s, &c);
  tab[i] = make_float2(c, s);
}

// ---------------------------------------------------------------------------
// bf16 MFMA GEMM:  C(MxN) = A(MxK) @ Bt(NxK)^T. 128x128 tile, BK=64, 4 waves.
// ---------------------------------------------------------------------------
template <bool BF16OUT>
__global__ __launch_bounds__(256) void gemm_bt(
    const u16* __restrict__ A, const u16* __restrict__ Bt,
    void* __restrict__ Cv, int M, int N, int K) {
  __shared__ u16 As[128 * 64] __attribute__((aligned(16)));
  __shared__ u16 Bs[128 * 64] __attribute__((aligned(16)));
  const int tid = threadIdx.x;
  const int w = tid >> 6, l = tid & 63;
  const int m0 = blockIdx.y * 128, n0 = blockIdx.x * 128;
  const int wr = (w >> 1) * 64, wc = (w & 1) * 64;
  const int srow = l >> 3;
  const int kgrp = ((l & 7) ^ srow) * 8;

  f32x4 acc[4][4] = {};

  for (int kt = 0; kt < K; kt += 64) {
    if (kt) __syncthreads();
#pragma unroll
    for (int i = 0; i < 4; ++i) {
      int c = w * 4 + i;
      int row = c * 8 + srow;
      gload16(A + (size_t)(m0 + row) * K + kt + kgrp, (char*)As + c * 1024);
      gload16(Bt + (size_t)(n0 + row) * K + kt + kgrp, (char*)Bs + c * 1024);
    }
    __syncthreads();
#pragma unroll
    for (int kk = 0; kk < 2; ++kk) {
      short8 af[4], bf[4];
#pragma unroll
      for (int i = 0; i < 4; ++i) {
        int ra = wr + i * 16 + (l & 15);
        int sa = kk * 4 + (l >> 4);
        af[i] = *(const short8*)((const char*)As + ra * 128 + ((sa ^ (ra & 7)) << 4));
        int rb = wc + i * 16 + (l & 15);
        bf[i] = *(const short8*)((const char*)Bs + rb * 128 + ((sa ^ (rb & 7)) << 4));
      }
#pragma unroll
      for (int i = 0; i < 4; ++i)
#pragma unroll
        for (int j = 0; j < 4; ++j)
          acc[i][j] = __builtin_amdgcn_mfma_f32_16x16x32_bf16(af[i], bf[j], acc[i][j], 0, 0, 0);
    }
  }
#pragma unroll
  for (int i = 0; i < 4; ++i) {
#pragma unroll
    for (int r = 0; r < 4; ++r) {
      size_t row = (size_t)(m0 + wr + i * 16 + (l >> 4) * 4 + r);
      size_t base = row * N + n0 + wc + (l & 15);
#pragma unroll
      for (int j = 0; j < 4; ++j) {
        if (BF16OUT) ((u16*)Cv)[base + j * 16] = f2bf(acc[i][j][r]);
        else         ((float*)Cv)[base + j * 16] = acc[i][j][r];
      }
    }
  }
}

// ---------------------------------------------------------------------------
// streaming pointwise: C [M][NC_] = (q|k|v|praw|dtraw). Wave per row.
// gamma from dt column; p/sigmoid; V*(1-p); RoPE; Q*SCALE; lg out.
// ---------------------------------------------------------------------------
__global__ __launch_bounds__(256) void pointwise_kernel(
    const u16* __restrict__ C, const float* __restrict__ b_dt,
    const float* __restrict__ b_gsp, const float2* __restrict__ tab,
    u16* __restrict__ Qb, u16* __restrict__ Kb, u16* __restrict__ Vb,
    float* __restrict__ lg) {
  const int row = blockIdx.x * 4 + (threadIdx.x >> 6);
  const int l = threadIdx.x & 63;
  const int b = row >> 11, t = row & (T_ - 1);
  const int h = l >> 2;
  const int dd0 = (l & 3) * 16;
  const int col = h * 64 + dd0;
  const size_t cb = (size_t)row * NC_;

  // gamma for this head (4 lanes redundant)
  float dtv = b2f(C[cb + 4096 + h]) + b_dt[h];
  float sp = (dtv > 20.f) ? dtv : log1pf(__expf(dtv));
  const float gh = __expf(-sp);

  const short8* qp = (const short8*)(C + cb + col);
  const short8* kp = (const short8*)(C + cb + 1024 + col);
  const short8* vp = (const short8*)(C + cb + 2048 + col);
  const short8* pp = (const short8*)(C + cb + 3072 + col);
  short8 q0 = qp[0], q1 = qp[1];
  short8 k0 = kp[0], k1 = kp[1];
  short8 v0 = vp[0], v1 = vp[1];
  short8 pr0 = pp[0], pr1 = pp[1];

  float ge = 0.f;
  short8 vo0, vo1;
#pragma unroll
  for (int i = 0; i < 8; ++i) {
    float pv = b2f((u16)pr0[i]) + b_gsp[col + i];
    float p = 1.f / (1.f + __expf(-pv));
    ge += gh * (1.f - p) + p;
    vo0[i] = (short)f2bf(b2f((u16)v0[i]) * (1.f - p));
    float pv1 = b2f((u16)pr1[i]) + b_gsp[col + 8 + i];
    float p1 = 1.f / (1.f + __expf(-pv1));
    ge += gh * (1.f - p1) + p1;
    vo1[i] = (short)f2bf(b2f((u16)v1[i]) * (1.f - p1));
  }
  const size_t hm = (((size_t)(b * H_ + h)) * T_ + t) * 64 + dd0;
  ((short8*)(Vb + hm))[0] = vo0;
  ((short8*)(Vb + hm))[1] = vo1;

  ge += __shfl_xor(ge, 1);
  ge += __shfl_xor(ge, 2);
  if ((l & 3) == 0) {
    float gs = ge * (1.f / 64.f);
    gs = fminf(fmaxf(gs, 1e-6f), 1.f - 1e-6f);
    lg[((size_t)(b * H_ + h)) * T_ + t] = logf(gs);
  }

  // RoPE; Q gets SCALE_ folded in
  short8 qo0, qo1, ko0, ko1;
  const float2* cs = tab + t * 32 + (dd0 >> 1);
#pragma unroll
  for (int m = 0; m < 4; ++m) {
    float2 c0 = cs[m];
    float qa = b2f((u16)q0[2 * m]), qb = b2f((u16)q0[2 * m + 1]);
    qo0[2 * m]     = (short)f2bf((qa * c0.x - qb * c0.y) * SCALE_);
    qo0[2 * m + 1] = (short)f2bf((qa * c0.y + qb * c0.x) * SCALE_);
    float ka = b2f((u16)k0[2 * m]), kb = b2f((u16)k0[2 * m + 1]);
    ko0[2 * m]     = (short)f2bf(ka * c0.x - kb * c0.y);
    ko0[2 * m + 1] = (short)f2bf(ka * c0.y + kb * c0.x);
    float2 c1 = cs[4 + m];
    float qa1 = b2f((u16)q1[2 * m]), qb1 = b2f((u16)q1[2 * m + 1]);
    qo1[2 * m]     = (short)f2bf((qa1 * c1.x - qb1 * c1.y) * SCALE_);
    qo1[2 * m + 1] = (short)f2bf((qa1 * c1.y + qb1 * c1.x) * SCALE_);
    float ka1 = b2f((u16)k1[2 * m]), kb1 = b2f((u16)k1[2 * m + 1]);
    ko1[2 * m]     = (short)f2bf(ka1 * c1.x - kb1 * c1.y);
    ko1[2 * m + 1] = (short)f2bf(ka1 * c1.y + kb1 * c1.x);
  }
  ((short8*)(Qb + hm))[0] = qo0; ((short8*)(Qb + hm))[1] = qo1;
  ((short8*)(Kb + hm))[0] = ko0; ((short8*)(Kb + hm))[1] = ko1;
}

// ---------------------------------------------------------------------------
// inclusive cumsum over T per (b,h)
// ---------------------------------------------------------------------------
__global__ __launch_bounds__(256) void scan_kernel(
    const float* __restrict__ lg, float* __restrict__ lgc) {
  const size_t base = (size_t)blockIdx.x * T_;
  const int tid = threadIdx.x;
  __shared__ float sums[256];
  float loc[8];
  float run = 0.f;
#pragma unroll
  for (int i = 0; i < 8; ++i) { run += lg[base + tid * 8 + i]; loc[i] = run; }
  sums[tid] = run;
  __syncthreads();
  if (tid == 0) {
    float r = 0.f;
    for (int i = 0; i < 256; ++i) { float v = sums[i]; sums[i] = r; r += v; }
  }
  __syncthreads();
  const float off = sums[tid];
#pragma unroll
  for (int i = 0; i < 8; ++i) lgc[base + tid * 8 + i] = off + loc[i];
}

// ---------------------------------------------------------------------------
// kv_prep (post-scan): K' = K * beta[s], beta = exp(lgc[tilebase]-lgc[s]);
// Vtg[bh][dd][t] = V[bh][t][dd]  (global transpose for attention B-staging)
// ---------------------------------------------------------------------------
__global__ __launch_bounds__(256) void kv_prep_kernel(
    const u16* __restrict__ Kb, const u16* __restrict__ Vb,
    const float* __restrict__ lgc, u16* __restrict__ Kp,
    u16* __restrict__ Vtg) {
  const int stile = blockIdx.x;   // 0..31
  const int bh = blockIdx.y;      // 0..31
  const int tid = threadIdx.x;
  __shared__ u16 vt[64][72];
  const size_t base = ((size_t)bh * T_ + (size_t)stile * 64) * 64;
  const float* lgp = lgc + (size_t)bh * T_;
  const float lgb = lgp[stile * 64];
#pragma unroll
  for (int i = 0; i < 2; ++i) {
    int c = tid * 2 + i;          // 0..511
    int row = c >> 3, k8 = (c & 7) * 8;
    float beta = __expf(lgb - lgp[stile * 64 + row]);
    short8 kv = *(const short8*)(Kb + base + row * 64 + k8);
    short8 ko;
#pragma unroll
    for (int j = 0; j < 8; ++j) ko[j] = (short)f2bf(b2f((u16)kv[j]) * beta);
    *(short8*)(Kp + base + row * 64 + k8) = ko;
    short8 vv = *(const short8*)(Vb + base + row * 64 + k8);
#pragma unroll
    for (int j = 0; j < 8; ++j) vt[row][k8 + j] = (u16)vv[j];
  }
  __syncthreads();
#pragma unroll
  for (int i = 0; i < 2; ++i) {
    int c = tid * 2 + i;
    int dd = c >> 3, t8 = (c & 7) * 8;
    short8 o;
#pragma unroll
    for (int j = 0; j < 8; ++j) o[j] = (short)vt[t8 + j][dd];
    *(short8*)(Vtg + ((size_t)bh * 64 + dd) * T_ + stile * 64 + t8) = o;
  }
}

// ---------------------------------------------------------------------------
// MFMA attention, decay-factorized. 1D grid, XCD-swizzled:
// block i -> xcd = i&7 owns heads {xcd, xcd+8, xcd+16, xcd+24} (K'+V^T fit L2).
// Swapped QK^T (C[s][q]); per-wave P buffer aliases Qs; V^T staged via gload16.
// ---------------------------------------------------------------------------
__global__ __launch_bounds__(256) void attn_mfma(
    const u16* __restrict__ Qb, const u16* __restrict__ Kp,
    const u16* __restrict__ Vtg, const float* __restrict__ lgc,
    u16* __restrict__ Y) {
  const int i = blockIdx.x;            // 0..1023
  const int tt = (i >> 3) & 31;
  const int bh = (i & 7) + ((i >> 8) << 3);
  const int b = bh >> 4, h = bh & 15;
  const int tid = threadIdx.x, w = tid >> 6, l = tid & 63;
  __shared__ u16 Qs[64 * 64] __attribute__((aligned(16)));   // reused as P
  __shared__ u16 Ks[64 * 64] __attribute__((aligned(16)));
  __shared__ u16 Vs[64 * 64] __attribute__((aligned(16)));   // V^T tile [dd][s]
  const u16* Qg = Qb + (size_t)bh * T_ * 64;
  const u16* Kg = Kp + (size_t)bh * T_ * 64;
  const u16* Vg = Vtg + (size_t)bh * 64 * T_;
  const float* lgp = lgc + (size_t)bh * T_;

  const int srow = l >> 3;
  const int kgrp = ((l & 7) ^ srow) * 8;
  const int ql = l & 15, g4 = l >> 4;

#pragma unroll
  for (int i2 = 0; i2 < 2; ++i2) {     // stage Q
    int c = w * 2 + i2;
    int row = c * 8 + srow;
    gload16(Qg + (size_t)(tt * 64 + row) * 64 + kgrp, (char*)Qs + c * 1024);
  }
  const float lgq = lgp[tt * 64 + w * 16 + ql];
  const float lgtop = lgp[tt * 64];
  __syncthreads();

  short8 qf[2];
#pragma unroll
  for (int kk = 0; kk < 2; ++kk) {
    int row = w * 16 + ql;
    int slot = kk * 4 + g4;
    qf[kk] = *(const short8*)((const char*)Qs + row * 128 + ((slot ^ (row & 7)) << 4));
  }
  char* Pw = (char*)Qs + w * 2048;     // per-wave 16x64 bf16 P buffer
  const int pswz = (ql & 7) << 4;

  f32x4 yacc[4] = {};

  for (int st = tt; st >= 0; --st) {
    if (st < tt && lgtop - lgp[st * 64 + 63] <= -20.f) break;
    __syncthreads();                   // prev compute done; Qs->P safe (iter 0)
#pragma unroll
    for (int i2 = 0; i2 < 2; ++i2) {
      int c = w * 2 + i2;
      int row = c * 8 + srow;
      gload16(Kg + (size_t)(st * 64 + row) * 64 + kgrp, (char*)Ks + c * 1024);
      gload16(Vg + (size_t)row * T_ + st * 64 + kgrp, (char*)Vs + c * 1024);
    }
    const float alpha = __expf(lgq - lgp[st * 64]);
    __syncthreads();

    const bool diag = (st == tt);
#pragma unroll
    for (int n = 0; n < 4; ++n) {      // QK^T swapped: C[s][q]
      f32x4 s = {};
#pragma unroll
      for (int kk = 0; kk < 2; ++kk) {
        int row = n * 16 + ql;
        int slot = kk * 4 + g4;
        short8 kf = *(const short8*)((const char*)Ks + row * 128 + ((slot ^ (row & 7)) << 4));
        s = __builtin_amdgcn_mfma_f32_16x16x32_bf16(kf, qf[kk], s, 0, 0, 0);
      }
      u16x4 pk;
#pragma unroll
      for (int r = 0; r < 4; ++r) {
        float pv = s[r] * alpha;
        if (diag && (n * 16 + g4 * 4 + r) > (w * 16 + ql)) pv = 0.f;
        pk[r] = f2bf(pv);
      }
      *(u16x4*)(Pw + ((ql * 128 + n * 32 + g4 * 8) ^ pswz)) = pk;
    }
#pragma unroll
    for (int kk = 0; kk < 2; ++kk) {   // PV: Y[q][dd]
      short8 pf = *(const short8*)(Pw + ((ql * 128 + kk * 64 + g4 * 16) ^ pswz));
#pragma unroll
      for (int n2 = 0; n2 < 4; ++n2) {
        int row = n2 * 16 + ql;
        int slot = kk * 4 + g4;
        short8 vf = *(const short8*)((const char*)Vs + row * 128 + ((slot ^ (row & 7)) << 4));
        yacc[n2] = __builtin_amdgcn_mfma_f32_16x16x32_bf16(pf, vf, yacc[n2], 0, 0, 0);
      }
    }
  }

#pragma unroll
  for (int n2 = 0; n2 < 4; ++n2)
#pragma unroll
    for (int r = 0; r < 4; ++r) {
      size_t row = (size_t)(b * T_) + tt * 64 + w * 16 + g4 * 4 + r;
      Y[row * INNER_ + h * 64 + n2 * 16 + ql] = f2bf(yacc[n2][r]);
    }
}

// ---------------------------------------------------------------------------
extern "C" void kernel_launch(void* const* d_in, const int* in_sizes, int n_in,
                              void* d_out, int out_size, void* d_ws, size_t ws_size,
                              hipStream_t stream) {
  const float* x        = (const float*)d_in[0];
  const float* W_qkv    = (const float*)d_in[1];
  const float* W_out    = (const float*)d_in[2];
  const float* W_dt     = (const float*)d_in[3];
  const float* b_dt     = (const float*)d_in[4];
  const float* W_gsp    = (const float*)d_in[5];
  const float* b_gsp    = (const float*)d_in[6];
  const float* inv_freq = (const float*)d_in[7];
  float* out = (float*)d_out;

  const int M = B_ * T_;  // 4096
  char* p = (char*)d_ws;
  auto alloc = [&](size_t bytes) {
    char* r = p; p += (bytes + 255) & ~(size_t)255; return r;
  };
  u16*    xb    = (u16*)alloc((size_t)M * D_ * 2);             // 8 MB
  u16*    Wcombt= (u16*)alloc((size_t)NC_ * D_ * 2);           // 8.25 MB
  u16*    Woutt = (u16*)alloc((size_t)D_ * INNER_ * 2);        // 2 MB
  u16*    Cqkvp = (u16*)alloc((size_t)M * NC_ * 2);            // 33 MB
  u16*    Qb    = (u16*)alloc((size_t)B_ * H_ * T_ * 64 * 2);  // 8 MB
  u16*    Kb    = (u16*)alloc((size_t)B_ * H_ * T_ * 64 * 2);
  u16*    Vb    = (u16*)alloc((size_t)B_ * H_ * T_ * 64 * 2);
  float*  lg    = (float*)alloc((size_t)B_ * H_ * T_ * 4);
  float*  lgc   = (float*)alloc((size_t)B_ * H_ * T_ * 4);
  float2* tab   = (float2*)alloc((size_t)T_ * 32 * 8);         // 512 KB
  // after pointwise, Cqkvp is dead -> alias attention buffers into it
  u16*    Kp    = Cqkvp;                                       // 8 MB
  u16*    Vtg   = Cqkvp + (size_t)4 * 1024 * 1024;             // 8 MB
  u16*    Yb    = Cqkvp + (size_t)8 * 1024 * 1024;             // 8 MB

  // prep
  cast_bf16_kernel<<<(M * D_ / 4 + 255) / 256, 256, 0, stream>>>(x, xb, M * D_ / 4);
  rope_tab_kernel<<<T_ * 32 / 256, 256, 0, stream>>>(inv_freq, tab);
  cast_transpose_kernel<<<dim3(3 * INNER_ / 64, D_ / 64), 256, 0, stream>>>(
      W_qkv, Wcombt, D_, 3 * INNER_);
  cast_transpose_kernel<<<dim3(INNER_ / 64, D_ / 64), 256, 0, stream>>>(
      W_gsp, Wcombt + (size_t)3 * INNER_ * D_, D_, INNER_);
  wdt_transpose_kernel<<<64, 256, 0, stream>>>(W_dt, Wcombt + (size_t)4096 * D_);
  cast_transpose_kernel<<<dim3(D_ / 64, INNER_ / 64), 256, 0, stream>>>(
      W_out, Woutt, INNER_, D_);

  // combined projection GEMM: [q|k|v|praw|dt] = x @ Wcomb  (N=4224)
  gemm_bt<true><<<dim3(NC_ / 128, M / 128), 256, 0, stream>>>(
      xb, Wcombt, Cqkvp, M, NC_, D_);

  pointwise_kernel<<<M / 4, 256, 0, stream>>>(Cqkvp, b_dt, b_gsp, tab,
                                              Qb, Kb, Vb, lg);
  scan_kernel<<<B_ * H_, 256, 0, stream>>>(lg, lgc);
  kv_prep_kernel<<<dim3(T_ / 64, B_ * H_), 256, 0, stream>>>(Kb, Vb, lgc, Kp, Vtg);

  attn_mfma<<<1024, 256, 0, stream>>>(Qb, Kp, Vtg, lgc, Yb);

  // out = Y @ W_out  (fp32 out)
  gemm_bt<false><<<dim3(D_ / 128, M / 128), 256, 0, stream>>>(
      Yb, Woutt, out, M, D_, INNER_);
}